// Round 9
// baseline (335.571 us; speedup 1.0000x reference)
//
#include <hip/hip_runtime.h>
#include <math.h>

#define NPIX 4096
#define CCH  128

typedef __attribute__((ext_vector_type(8))) short  bf8;   // 8 bf16 in 4 VGPRs
typedef __attribute__((ext_vector_type(4))) float  f4;

#define MFMA(a, b, c) __builtin_amdgcn_mfma_f32_16x16x32_bf16(a, b, c, 0, 0, 0)

__device__ __forceinline__ unsigned short f2bf(float x) {
    union { float f; unsigned u; } v; v.f = x;
    unsigned r = v.u + 0x7fffu + ((v.u >> 16) & 1u);   // RNE
    return (unsigned short)(r >> 16);
}
// pack two floats to bf16x2 (lo in low short), half-ulp RNE, 3 VALU ops
__device__ __forceinline__ unsigned pk2r(float lo, float hi) {
    union { float f; unsigned u; } a, b; a.f = hi; b.f = lo;
    return __builtin_amdgcn_perm(a.u + 0x8000u, b.u + 0x8000u, 0x07060302u);
}
// truncating pack, 1 VALU op (P only: O and l share the same packed P, bias cancels)
__device__ __forceinline__ unsigned pk2t(float lo, float hi) {
    union { float f; unsigned u; } a, b; a.f = hi; b.f = lo;
    return __builtin_amdgcn_perm(a.u, b.u, 0x07060302u);
}
__device__ __forceinline__ float asf(unsigned u) {
    union { unsigned u; float f; } v; v.u = u; return v.f;
}

// Workspace layout (bytes), 32 MB:
//   lbuf 0..1M        fp32 4 slices [bh][n]   (flash out)
//   wqb  1.25M        bf16 [384][128]  (q rows pre-scaled by 32^-.5*log2e)
//   wob  1.75M        bf16 [128][128]
//   qh   4..8M        bf16 [bh][n][32]
//   kh   8..12M       bf16 [bh][n][32]
//   vth  12..16M      bf16 [bh*32+d][n]
//   aob  16..32M      bf16 4 slices, [bh][q][32d] rows (unnormalized O partials)

// ---------------------------------------------------------------------------
// Kernel 0: convert weights to bf16 (q rows scaled). grid 256 x 256.
// ---------------------------------------------------------------------------
__global__ __launch_bounds__(256) void wconv_kernel(
    const float* __restrict__ wq, const float* __restrict__ wo,
    unsigned short* __restrict__ wqb, unsigned short* __restrict__ wob)
{
    const float qs2 = 0.17677669529663687f * 1.4426950408889634f;
    int i = blockIdx.x * 256 + threadIdx.x;       // 0..65535
    if (i < 49152) {
        float f = wq[i];
        if (i < 16384) f *= qs2;                  // q rows 0..127
        wqb[i] = f2bf(f);
    } else {
        int j = i - 49152;
        wob[j] = f2bf(wo[j]);
    }
}

// ---------------------------------------------------------------------------
// Kernel 1: fused LayerNorm + QKV MFMA GEMM, ZERO barriers.
// grid (256, 3) x 256 thr. Wave = 16 px, fully independent: in-wave LN via
// shfl, wave-private LDS xnb, 8 o-tiles per wave (part: 0=q, 1=k, 2=v).
// ---------------------------------------------------------------------------
__global__ __launch_bounds__(256) void lnqkv_kernel(
    const float* __restrict__ x, const float* __restrict__ g,
    const float* __restrict__ bvec, const unsigned short* __restrict__ wqb,
    unsigned short* __restrict__ qh, unsigned short* __restrict__ kh,
    unsigned short* __restrict__ vth)
{
    const int t    = threadIdx.x;
    const int wv   = t >> 6;
    const int l16  = t & 15;
    const int quad = (t & 63) >> 4;
    const int part = blockIdx.y;                 // 0=q, 1=k, 2=v
    const int pxg  = blockIdx.x * 4 + wv;        // 0..1023
    const int b  = pxg >> 8;
    const int n0 = (pxg & 255) << 4;

    // wave-private xnb: 16 rows x 70 dwords (stride even -> aligned b64 reads)
    __shared__ unsigned xnb_raw[4][16 * 70];
    unsigned* xnb = xnb_raw[wv];

    // load 32 c-values for px = n0+l16, c = quad*32+i ; accumulate stats
    const float* xb = x + (size_t)b * CCH * NPIX + n0 + l16;
    float v[32];
    float s = 0.f, s2 = 0.f;
#pragma unroll
    for (int i = 0; i < 32; ++i) {
        v[i] = xb[(size_t)(quad * 32 + i) * NPIX];
        s += v[i]; s2 += v[i] * v[i];
    }
    // in-wave reduction across quads (lane bits 4,5)
    s  += __shfl_xor(s, 16, 64);  s  += __shfl_xor(s, 32, 64);
    s2 += __shfl_xor(s2, 16, 64); s2 += __shfl_xor(s2, 32, 64);
    const float mu  = s * (1.f / 128.f);
    const float var = s2 * (1.f / 128.f) - mu * mu;
    const float rs  = rsqrtf(var + 1e-5f);

    // normalize + affine + pack to wave-private LDS
#pragma unroll
    for (int j = 0; j < 16; ++j) {
        const int c = quad * 32 + 2 * j;
        float f0 = (v[2 * j]     - mu) * rs * g[c]     + bvec[c];
        float f1 = (v[2 * j + 1] - mu) * rs * g[c + 1] + bvec[c + 1];
        xnb[l16 * 70 + quad * 16 + j] = pk2r(f0, f1);
    }

    // B-frags (reused across all 8 o-tiles): lane (quad,l16), k-step kk
    union { uint2 u2[2]; bf8 v; } bx[4];
#pragma unroll
    for (int kk = 0; kk < 4; ++kk) {
        const int base = l16 * 70 + kk * 16 + quad * 4;
        bx[kk].u2[0] = *(uint2*)&xnb[base];
        bx[kk].u2[1] = *(uint2*)&xnb[base + 2];
    }

    // 8 o-tiles of this part
    for (int ot2 = 0; ot2 < 8; ++ot2) {
        const int ot = part * 8 + ot2;
        const unsigned short* wr = wqb + (size_t)(ot * 16 + l16) * CCH;
        f4 acc = {0.f, 0.f, 0.f, 0.f};
#pragma unroll
        for (int kk = 0; kk < 4; ++kk) {
            const bf8 a = *(const bf8*)&wr[kk * 32 + quad * 8];
            acc = MFMA(a, bx[kk].v, acc);
        }
        // C-frag: col(px)=l16, row = quad*4+r ; h = ot2>>1, d0 = (ot2&1)*16+quad*4
        const int h  = ot2 >> 1;
        const int bh = b * 4 + h;
        if (part < 2) {
            const int d0 = (ot2 & 1) * 16 + quad * 4;
            unsigned short* dst = ((part == 0) ? qh : kh)
                                + ((size_t)bh * NPIX + n0 + l16) * 32 + d0;
            uint2 wp;
            wp.x = pk2r(acc.x, acc.y);
            wp.y = pk2r(acc.z, acc.w);
            *(uint2*)dst = wp;
        } else {
            const int dv = (ot2 & 1) * 16 + quad * 4;
#pragma unroll
            for (int r = 0; r < 4; ++r)
                vth[((size_t)bh * 32 + dv + r) * NPIX + n0 + l16] = f2bf(acc[r]);
        }
    }
}

// ---------------------------------------------------------------------------
// Kernel 2: MFMA flash attention — split-K 4 (8 waves/SIMD), 64-key tiles,
// bf16 O partials in [bh][q][32d] rows (full-line coverage per wave).
// grid 16bh x 32qt x 4ks = 2048 blocks, XCD-swizzled.
// ---------------------------------------------------------------------------
struct F64 { bf8 k0, k1, k2, k3, v0a, v1a, v0b, v1b; };

__device__ __forceinline__ void load64(F64& f,
    const unsigned short* __restrict__ khb, const unsigned short* __restrict__ vhb,
    int j0, int l16, int quad)
{
    const size_t ka = (size_t)(j0 + l16) * 32 + quad * 8;
    f.k0 = *(const bf8*)&khb[ka];
    f.k1 = *(const bf8*)&khb[ka + 16 * 32];
    f.k2 = *(const bf8*)&khb[ka + 32 * 32];
    f.k3 = *(const bf8*)&khb[ka + 48 * 32];
    const size_t va = (size_t)l16 * NPIX + j0 + quad * 8;
    f.v0a = *(const bf8*)&vhb[va];
    f.v1a = *(const bf8*)&vhb[va + (size_t)16 * NPIX];
    f.v0b = *(const bf8*)&vhb[va + 32];
    f.v1b = *(const bf8*)&vhb[va + (size_t)16 * NPIX + 32];
}

__device__ __forceinline__ void compute64(const F64& f,
    const bf8 qA, const bf8 qB, const bf8 ones,
    f4& o00, f4& o10, f4& o01, f4& o11, f4& lA, f4& lB,
    unsigned short (*pbA)[72], unsigned short (*pbB)[72], int l16, int quad)
{
    const f4 z = {0.f, 0.f, 0.f, 0.f};
    f4 sA0 = MFMA(f.k0, qA, z);
    f4 sA1 = MFMA(f.k1, qA, z);
    f4 sA2 = MFMA(f.k2, qA, z);
    f4 sA3 = MFMA(f.k3, qA, z);
    f4 sB0 = MFMA(f.k0, qB, z);
    f4 sB1 = MFMA(f.k1, qB, z);
    f4 sB2 = MFMA(f.k2, qB, z);
    f4 sB3 = MFMA(f.k3, qB, z);

    unsigned* prA = (unsigned*)&pbA[l16][0];
    unsigned* prB = (unsigned*)&pbB[l16][0];
    const int w0 = quad * 2;
#define EXPPK(dst, s, base)                                                    \
    dst[base + w0]     = pk2t(__builtin_amdgcn_exp2f(s.x),                     \
                              __builtin_amdgcn_exp2f(s.y));                    \
    dst[base + w0 + 1] = pk2t(__builtin_amdgcn_exp2f(s.z),                     \
                              __builtin_amdgcn_exp2f(s.w));
    EXPPK(prA, sA0, 0)  EXPPK(prA, sA1, 8)  EXPPK(prA, sA2, 16) EXPPK(prA, sA3, 24)
    EXPPK(prB, sB0, 0)  EXPPK(prB, sB1, 8)  EXPPK(prB, sB2, 16) EXPPK(prB, sB3, 24)
#undef EXPPK

    const bf8 pAa = *(const bf8*)&pbA[l16][quad * 8];
    const bf8 pAb = *(const bf8*)&pbA[l16][32 + quad * 8];
    const bf8 pBa = *(const bf8*)&pbB[l16][quad * 8];
    const bf8 pBb = *(const bf8*)&pbB[l16][32 + quad * 8];

    o00 = MFMA(f.v0a, pAa, o00); o10 = MFMA(f.v1a, pAa, o10);
    o00 = MFMA(f.v0b, pAb, o00); o10 = MFMA(f.v1b, pAb, o10);
    o01 = MFMA(f.v0a, pBa, o01); o11 = MFMA(f.v1a, pBa, o11);
    o01 = MFMA(f.v0b, pBb, o01); o11 = MFMA(f.v1b, pBb, o11);
    lA  = MFMA(ones, pAa, lA);   lA  = MFMA(ones, pAb, lA);
    lB  = MFMA(ones, pBa, lB);   lB  = MFMA(ones, pBb, lB);
}

__global__ __launch_bounds__(256, 8) void flash_kernel(
    const unsigned short* __restrict__ qh, const unsigned short* __restrict__ kh,
    const unsigned short* __restrict__ vth,
    unsigned short* __restrict__ aob, float* __restrict__ lbuf)
{
    const int blk = blockIdx.x;
    const int bh  = (blk & 7) + 8 * ((blk >> 3) & 1);   // XCD-local per bh
    const int rem = blk >> 4;
    const int qt  = rem & 31;
    const int ks  = rem >> 5;                            // 0..3
    const int t   = threadIdx.x;
    const int wv  = t >> 6;
    const int l16 = t & 15;
    const int quad = (t & 63) >> 4;
    const int q0  = qt * 128 + wv * 32;

    __shared__ unsigned short pbuf_raw[4][2][16][72];   // 18 KB -> 8 blocks/CU
    unsigned short (*pbA)[72] = pbuf_raw[wv][0];
    unsigned short (*pbB)[72] = pbuf_raw[wv][1];

    const size_t qbaseA = ((size_t)bh * NPIX + q0 + l16) * 32 + quad * 8;
    const bf8 qA = *(const bf8*)&qh[qbaseA];
    const bf8 qB = *(const bf8*)&qh[qbaseA + 16 * 32];

    const unsigned short* khb = kh  + (size_t)bh * NPIX * 32;
    const unsigned short* vhb = vth + (size_t)bh * 32 * NPIX;

    const short one = (short)0x3f80;
    const bf8 ones = {one, one, one, one, one, one, one, one};

    const f4 z = {0.f, 0.f, 0.f, 0.f};
    f4 o00 = z, o10 = z, o01 = z, o11 = z, lA = z, lB = z;

    const int jbase = ks * 1024;
    F64 fa, fb;
    load64(fa, khb, vhb, jbase, l16, quad);
    for (int off = 0; off < 1024; off += 128) {
        load64(fb, khb, vhb, jbase + off + 64, l16, quad);
        compute64(fa, qA, qB, ones, o00, o10, o01, o11, lA, lB, pbA, pbB, l16, quad);
        load64(fa, khb, vhb, jbase + off + 128, l16, quad);  // tail over-read stays in ws
        compute64(fb, qA, qB, ones, o00, o10, o01, o11, lA, lB, pbA, pbB, l16, quad);
    }

    // epilogue: bf16 O rows [bh][q][32d] — each q-row (64 B) fully covered by
    // the 4 quads; rows q0+l16.. contiguous -> full 128B lines, no RMW.
    unsigned short* aos = aob + (size_t)ks * 2097152;
    unsigned short* rowA = aos + ((size_t)bh * NPIX + q0 + l16) * 32;
    uint2 wA0, wA1, wB0, wB1;
    wA0.x = pk2r(o00.x, o00.y); wA0.y = pk2r(o00.z, o00.w);
    wA1.x = pk2r(o10.x, o10.y); wA1.y = pk2r(o10.z, o10.w);
    wB0.x = pk2r(o01.x, o01.y); wB0.y = pk2r(o01.z, o01.w);
    wB1.x = pk2r(o11.x, o11.y); wB1.y = pk2r(o11.z, o11.w);
    *(uint2*)&rowA[quad * 4]      = wA0;
    *(uint2*)&rowA[16 + quad * 4] = wA1;
    unsigned short* rowB = rowA + 16 * 32;
    *(uint2*)&rowB[quad * 4]      = wB0;
    *(uint2*)&rowB[16 + quad * 4] = wB1;

    if (quad == 0) {
        float* lbs = lbuf + (size_t)ks * 65536;
        lbs[(size_t)bh * NPIX + q0 + l16]      = lA.x;
        lbs[(size_t)bh * NPIX + q0 + 16 + l16] = lB.x;
    }
}

// ---------------------------------------------------------------------------
// Kernel 3: sum 4 bf16 O-slices ([bh][q][32d] rows), normalize, MFMA
// projection + bias. grid (512, 2), 32 px/block, ONE barrier.
// ---------------------------------------------------------------------------
__global__ __launch_bounds__(256) void proj_kernel(
    const unsigned short* __restrict__ aob, const float* __restrict__ lbuf,
    const unsigned short* __restrict__ wob, const float* __restrict__ b_out,
    float* __restrict__ out)
{
    const int blk  = blockIdx.x;
    const int part = blockIdx.y;
    const int b  = blk >> 7;
    const int n0 = (blk & 127) << 5;
    const int t  = threadIdx.x;
    const int wv = t >> 6;
    const int l16 = t & 15;
    const int quad = (t & 63) >> 4;

    __shared__ unsigned short xsb[32 * 138];   // [pix][c], stride 138

    // load stage: thread -> (h = t>>6, px = (t>>1)&31, dhalf = t&1)
    {
        const int h = t >> 6, px = (t >> 1) & 31, dhalf = t & 1;
        const size_t qrow = ((size_t)(b * 4 + h) * NPIX + n0 + px) * 32 + dhalf * 16;
        float a16[16];
#pragma unroll
        for (int i = 0; i < 16; ++i) a16[i] = 0.f;
#pragma unroll
        for (int s = 0; s < 4; ++s) {
            const unsigned short* src = aob + (size_t)s * 2097152 + qrow;
            const uint4 u0 = *(const uint4*)&src[0];
            const uint4 u1 = *(const uint4*)&src[8];
            const unsigned uu[8] = {u0.x, u0.y, u0.z, u0.w, u1.x, u1.y, u1.z, u1.w};
#pragma unroll
            for (int j = 0; j < 8; ++j) {
                a16[2 * j]     += asf(uu[j] << 16);
                a16[2 * j + 1] += asf(uu[j] & 0xffff0000u);
            }
        }
        const size_t li = (size_t)(b * 4 + h) * NPIX + n0 + px;
        const float linv = 1.0f / (lbuf[li] + lbuf[li + 65536]
                                 + lbuf[li + 131072] + lbuf[li + 196608]);
        unsigned* xd = (unsigned*)xsb;
        const int cbase = px * 69 + h * 16 + dhalf * 8;
#pragma unroll
        for (int j = 0; j < 8; ++j)
            xd[cbase + j] = pk2r(a16[2 * j] * linv, a16[2 * j + 1] * linv);
    }
    __syncthreads();

    // A-frags: wob rows (o = o0 + l16), bf16 direct
    const int o0 = part * 64 + wv * 16;
    const unsigned short* wrow = wob + (size_t)(o0 + l16) * CCH;
    bf8 aw[4];
#pragma unroll
    for (int kk = 0; kk < 4; ++kk)
        aw[kk] = *(const bf8*)&wrow[kk * 32 + quad * 8];

    const f4 z = {0.f, 0.f, 0.f, 0.f};
    f4 acc[2] = {z, z};
#pragma unroll
    for (int s = 0; s < 2; ++s) {
#pragma unroll
        for (int kk = 0; kk < 4; ++kk) {
            const unsigned short* row = &xsb[(s * 16 + l16) * 138 + kk * 32 + quad * 8];
            union { unsigned u[4]; bf8 v; } pb;
            pb.u[0] = *(const unsigned*)&row[0];
            pb.u[1] = *(const unsigned*)&row[2];
            pb.u[2] = *(const unsigned*)&row[4];
            pb.u[3] = *(const unsigned*)&row[6];
            acc[s] = MFMA(aw[kk], pb.v, acc[s]);
        }
    }

#pragma unroll
    for (int r = 0; r < 4; ++r) {
        const int o = o0 + quad * 4 + r;
        const float bo = b_out[o];
        float* orow = out + (size_t)(b * CCH + o) * NPIX + n0 + l16;
#pragma unroll
        for (int s = 0; s < 2; ++s)
            orow[s * 16] = acc[s][r] + bo;
    }
}

// ---------------------------------------------------------------------------
extern "C" void kernel_launch(void* const* d_in, const int* in_sizes, int n_in,
                              void* d_out, int out_size, void* d_ws, size_t ws_size,
                              hipStream_t stream) {
    const float* x     = (const float*)d_in[0];
    const float* g     = (const float*)d_in[1];
    const float* bvec  = (const float*)d_in[2];
    const float* w_qkv = (const float*)d_in[3];
    const float* w_out = (const float*)d_in[4];
    const float* b_out = (const float*)d_in[5];
    float* out = (float*)d_out;

    char* ws = (char*)d_ws;
    float*          lbuf = (float*)(ws);                        // 0..1M (4 slices)
    unsigned short* wqb  = (unsigned short*)(ws + 0x140000);    // 1.25M
    unsigned short* wob  = (unsigned short*)(ws + 0x1C0000);    // 1.75M
    unsigned short* qh   = (unsigned short*)(ws + (4u  << 20));
    unsigned short* kh   = (unsigned short*)(ws + (8u  << 20));
    unsigned short* vth  = (unsigned short*)(ws + (12u << 20));
    unsigned short* aob  = (unsigned short*)(ws + (16u << 20)); // 4 slices x 4MB

    wconv_kernel<<<dim3(256),     dim3(256), 0, stream>>>(w_qkv, w_out, wqb, wob);
    lnqkv_kernel<<<dim3(256, 3),  dim3(256), 0, stream>>>(x, g, bvec, wqb, qh, kh, vth);
    flash_kernel<<<dim3(2048),    dim3(256), 0, stream>>>(qh, kh, vth, aob, lbuf);
    proj_kernel <<<dim3(512, 2),  dim3(256), 0, stream>>>(aob, lbuf, wob, b_out, out);
}

// Round 10
// 187.030 us; speedup vs baseline: 1.7942x; 1.7942x over previous
//
#include <hip/hip_runtime.h>
#include <math.h>

#define NPIX 4096
#define CCH  128

typedef __attribute__((ext_vector_type(8))) short  bf8;   // 8 bf16 in 4 VGPRs
typedef __attribute__((ext_vector_type(4))) float  f4;

#define MFMA(a, b, c) __builtin_amdgcn_mfma_f32_16x16x32_bf16(a, b, c, 0, 0, 0)

__device__ __forceinline__ unsigned short f2bf(float x) {
    union { float f; unsigned u; } v; v.f = x;
    unsigned r = v.u + 0x7fffu + ((v.u >> 16) & 1u);   // RNE
    return (unsigned short)(r >> 16);
}
// pack two floats to bf16x2 (lo in low short), half-ulp RNE, 3 VALU ops
__device__ __forceinline__ unsigned pk2r(float lo, float hi) {
    union { float f; unsigned u; } a, b; a.f = hi; b.f = lo;
    return __builtin_amdgcn_perm(a.u + 0x8000u, b.u + 0x8000u, 0x07060302u);
}
// truncating pack, 1 VALU op. Used ONLY for P in flash: O and l consume the
// same packed P, so the common truncation bias cancels in O/l.
__device__ __forceinline__ unsigned pk2t(float lo, float hi) {
    union { float f; unsigned u; } a, b; a.f = hi; b.f = lo;
    return __builtin_amdgcn_perm(a.u, b.u, 0x07060302u);
}

// Workspace layout (bytes), 32 MB:
//   lbuf 0..512K     fp32 2 slices [bh][n]   (flash out)
//   wqb  1M..1.094M  bf16 [384][128]  (q rows pre-scaled by 32^-.5*log2e)
//   wob  1.5M..1.53M bf16 [128][128]
//   qh   4..8M       bf16 [bh][n][32]
//   kh   8..12M      bf16 [bh][n][32]
//   vth  12..16M     bf16 [bh*32+d][n]
//   ao   16..32M     fp32 2 slices [bh*32+d][n]

// ---------------------------------------------------------------------------
// Kernel 0: convert weights to bf16 (q rows scaled). grid 256 x 256.
// ---------------------------------------------------------------------------
__global__ __launch_bounds__(256) void wconv_kernel(
    const float* __restrict__ wq, const float* __restrict__ wo,
    unsigned short* __restrict__ wqb, unsigned short* __restrict__ wob)
{
    const float qs2 = 0.17677669529663687f * 1.4426950408889634f;
    int i = blockIdx.x * 256 + threadIdx.x;       // 0..65535
    if (i < 49152) {
        float f = wq[i];
        if (i < 16384) f *= qs2;                  // q rows 0..127
        wqb[i] = f2bf(f);
    } else {
        int j = i - 49152;
        wob[j] = f2bf(wo[j]);
    }
}

// ---------------------------------------------------------------------------
// Kernel 1: fused LayerNorm + QKV MFMA GEMM. grid (1024, 2) x 256 thr.
// 16 px/block; blockIdx.y splits the 24 o-tiles (3 per wave) -> 8 blocks/CU.
// (R7-proven config.)
// ---------------------------------------------------------------------------
__global__ __launch_bounds__(256, 8) void lnqkv_kernel(
    const float* __restrict__ x, const float* __restrict__ g,
    const float* __restrict__ bvec, const unsigned short* __restrict__ wqb,
    unsigned short* __restrict__ qh, unsigned short* __restrict__ kh,
    unsigned short* __restrict__ vth)
{
    const int blk  = blockIdx.x;
    const int part = blockIdx.y;        // 0: o-tiles 0..11, 1: 12..23
    const int b  = blk >> 8;
    const int n0 = (blk & 255) << 4;
    const int t  = threadIdx.x;

    __shared__ float xs[CCH * 17];             // [c][pix], stride 17
    __shared__ float red0[16][16];
    __shared__ float red1[16][16];
    __shared__ float mean_s[16];
    __shared__ float rstd_s[16];
    __shared__ unsigned short xnb[16 * 138];   // bf16 [pix][c], stride 138

    const float* xb = x + (size_t)b * CCH * NPIX + n0;
#pragma unroll
    for (int k = 0; k < 8; ++k) {
        int e = k * 256 + t;
        int c = e >> 4, p = e & 15;
        xs[c * 17 + p] = xb[(size_t)c * NPIX + p];
    }
    __syncthreads();

    {
        int pix = t & 15, cg = t >> 4;
        float s = 0.f, s2 = 0.f;
#pragma unroll
        for (int cc = 0; cc < 8; ++cc) {
            float v = xs[(cg * 8 + cc) * 17 + pix];
            s += v; s2 += v * v;
        }
        red0[cg][pix] = s; red1[cg][pix] = s2;
    }
    __syncthreads();
    if (t < 16) {
        float s = 0.f, s2 = 0.f;
#pragma unroll
        for (int cg = 0; cg < 16; ++cg) { s += red0[cg][t]; s2 += red1[cg][t]; }
        float mu  = s * (1.f / 128.f);
        float var = s2 * (1.f / 128.f) - mu * mu;
        mean_s[t] = mu;
        rstd_s[t] = rsqrtf(var + 1e-5f);
    }
    __syncthreads();

    // normalize + pack into LDS: thread -> (pix = t>>4, c0 = (t&15)*8)
    {
        const int pix = t >> 4;
        const int c0  = (t & 15) * 8;
        const float mu = mean_s[pix], rs = rstd_s[pix];
#pragma unroll
        for (int i = 0; i < 4; ++i) {
            int c = c0 + 2 * i;
            float f0 = (xs[c * 17 + pix]       - mu) * rs * g[c]     + bvec[c];
            float f1 = (xs[(c + 1) * 17 + pix] - mu) * rs * g[c + 1] + bvec[c + 1];
            *(unsigned*)&xnb[pix * 138 + c] = pk2r(f0, f1);
        }
    }
    __syncthreads();

    // MFMA GEMM: wave wv covers 3 o-tiles of this part.
    const int wv   = t >> 6;
    const int l16  = t & 15;
    const int quad = (t & 63) >> 4;

    for (int it = 0; it < 3; ++it) {
        const int ot = part * 12 + wv * 3 + it;   // 0-7 q, 8-15 k, 16-23 v
        const unsigned short* wr = wqb + (size_t)(ot * 16 + l16) * CCH;
        f4 acc = {0.f, 0.f, 0.f, 0.f};
#pragma unroll
        for (int kk = 0; kk < 4; ++kk) {
            const bf8 a = *(const bf8*)&wr[kk * 32 + quad * 8];
            const unsigned short* xr = &xnb[l16 * 138 + kk * 32 + quad * 8];
            union { unsigned u[4]; bf8 v; } bx;
            bx.u[0] = *(const unsigned*)&xr[0];
            bx.u[1] = *(const unsigned*)&xr[2];
            bx.u[2] = *(const unsigned*)&xr[4];
            bx.u[3] = *(const unsigned*)&xr[6];
            acc = MFMA(a, bx.v, acc);
        }
        // C-frag: col(px)=l16, row o = ot*16 + quad*4 + r
        if (ot < 16) {
            const int h  = (ot >> 1) & 3;
            const int d0 = (ot & 1) * 16 + quad * 4;
            const int bh = b * 4 + h;
            unsigned short* dst = ((ot < 8) ? qh : kh)
                                + ((size_t)bh * NPIX + n0 + l16) * 32 + d0;
            uint2 wp;
            wp.x = pk2r(acc.x, acc.y);
            wp.y = pk2r(acc.z, acc.w);
            *(uint2*)dst = wp;
        } else {
            const int bh = b * 4 + ((ot - 16) >> 1);
            const int dv = ((ot - 16) & 1) * 16 + quad * 4;
#pragma unroll
            for (int r = 0; r < 4; ++r)
                vth[((size_t)bh * 32 + dv + r) * NPIX + n0 + l16] = f2bf(acc[r]);
        }
    }
}

// ---------------------------------------------------------------------------
// Kernel 2: MFMA flash attention — R7 config (split-K 2, fp32 full-line
// stores, grid 1024 = 4 blk/CU, XCD-swizzled) + PARITY-DOUBLE-BUFFERED pbuf
// so consecutive tiles touch disjoint LDS (scheduler can overlap tile n+1's
// S/exp/pack/writes with tile n's LDS read-wait), and b64 LDS writes.
// ---------------------------------------------------------------------------
struct Frags { bf8 k0, k1, v0, v1; };

__device__ __forceinline__ void loadFrags(Frags& f,
    const unsigned short* __restrict__ khb, const unsigned short* __restrict__ vhb,
    int j0, int l16, int quad)
{
    const size_t ka0 = (size_t)(j0 + l16) * 32 + quad * 8;
    f.k0 = *(const bf8*)&khb[ka0];
    f.k1 = *(const bf8*)&khb[ka0 + 16 * 32];
    const size_t va0 = (size_t)l16 * NPIX + j0 + quad * 8;
    f.v0 = *(const bf8*)&vhb[va0];
    f.v1 = *(const bf8*)&vhb[va0 + (size_t)16 * NPIX];
}

__device__ __forceinline__ void tileCompute(const Frags& f,
    const bf8 qA, const bf8 qB, const bf8 ones,
    f4& o00, f4& o10, f4& o01, f4& o11, f4& lA, f4& lB,
    unsigned short (*pbA)[56], unsigned short (*pbB)[56], int l16, int quad)
{
    const f4 z = {0.f, 0.f, 0.f, 0.f};
    f4 sA0 = MFMA(f.k0, qA, z);
    f4 sA1 = MFMA(f.k1, qA, z);
    f4 sB0 = MFMA(f.k0, qB, z);
    f4 sB1 = MFMA(f.k1, qB, z);

    float pA0 = __builtin_amdgcn_exp2f(sA0.x), pA1 = __builtin_amdgcn_exp2f(sA0.y);
    float pA2 = __builtin_amdgcn_exp2f(sA0.z), pA3 = __builtin_amdgcn_exp2f(sA0.w);
    float pA4 = __builtin_amdgcn_exp2f(sA1.x), pA5 = __builtin_amdgcn_exp2f(sA1.y);
    float pA6 = __builtin_amdgcn_exp2f(sA1.z), pA7 = __builtin_amdgcn_exp2f(sA1.w);
    float pB0 = __builtin_amdgcn_exp2f(sB0.x), pB1 = __builtin_amdgcn_exp2f(sB0.y);
    float pB2 = __builtin_amdgcn_exp2f(sB0.z), pB3 = __builtin_amdgcn_exp2f(sB0.w);
    float pB4 = __builtin_amdgcn_exp2f(sB1.x), pB5 = __builtin_amdgcn_exp2f(sB1.y);
    float pB6 = __builtin_amdgcn_exp2f(sB1.z), pB7 = __builtin_amdgcn_exp2f(sB1.w);

    // transpose P via wave-private LDS, b64 writes (8B aligned: rows 112 B)
    uint2 wa0; wa0.x = pk2t(pA0, pA1); wa0.y = pk2t(pA2, pA3);
    uint2 wa1; wa1.x = pk2t(pA4, pA5); wa1.y = pk2t(pA6, pA7);
    uint2 wb0; wb0.x = pk2t(pB0, pB1); wb0.y = pk2t(pB2, pB3);
    uint2 wb1; wb1.x = pk2t(pB4, pB5); wb1.y = pk2t(pB6, pB7);
    *(uint2*)&pbA[l16][quad * 4]      = wa0;   // keys quad*4+0..3
    *(uint2*)&pbA[l16][16 + quad * 4] = wa1;   // keys 16+quad*4+0..3
    *(uint2*)&pbB[l16][quad * 4]      = wb0;
    *(uint2*)&pbB[l16][16 + quad * 4] = wb1;

    const bf8 pfA = *(const bf8*)&pbA[l16][quad * 8];
    const bf8 pfB = *(const bf8*)&pbB[l16][quad * 8];

    o00 = MFMA(f.v0, pfA, o00); o10 = MFMA(f.v1, pfA, o10);
    o01 = MFMA(f.v0, pfB, o01); o11 = MFMA(f.v1, pfB, o11);
    lA  = MFMA(ones, pfA, lA);  lB  = MFMA(ones, pfB, lB);
}

__global__ __launch_bounds__(256, 4) void flash_kernel(
    const unsigned short* __restrict__ qh, const unsigned short* __restrict__ kh,
    const unsigned short* __restrict__ vth,
    float* __restrict__ ao, float* __restrict__ lbuf)
{
    const int blk = blockIdx.x;
    const int bh  = (blk & 7) + 8 * ((blk >> 3) & 1);   // XCD-local per bh
    const int rem = blk >> 4;
    const int qt  = rem & 31;
    const int ks  = rem >> 5;                            // 0..1
    const int t   = threadIdx.x;
    const int wv  = t >> 6;
    const int l16 = t & 15;
    const int quad = (t & 63) >> 4;
    const int q0  = qt * 128 + wv * 32;

    // [wave][parity][A/B][q][56] — 28 KB, 4 blocks/CU -> 112 KB LDS/CU
    __shared__ unsigned short pbuf_raw[4][2][2][16][56];

    const size_t qbaseA = ((size_t)bh * NPIX + q0 + l16) * 32 + quad * 8;
    const bf8 qA = *(const bf8*)&qh[qbaseA];
    const bf8 qB = *(const bf8*)&qh[qbaseA + 16 * 32];

    const unsigned short* khb = kh  + (size_t)bh * NPIX * 32;
    const unsigned short* vhb = vth + (size_t)bh * 32 * NPIX;

    const short one = (short)0x3f80;
    const bf8 ones = {one, one, one, one, one, one, one, one};

    const f4 z = {0.f, 0.f, 0.f, 0.f};
    f4 o00 = z, o10 = z, o01 = z, o11 = z, lA = z, lB = z;

    const int jbase = ks * 2048;
    Frags fa, fb;
    loadFrags(fa, khb, vhb, jbase, l16, quad);
    for (int jt = 0; jt < 64; jt += 2) {
        loadFrags(fb, khb, vhb, jbase + (jt + 1) * 32, l16, quad);
        tileCompute(fa, qA, qB, ones, o00, o10, o01, o11, lA, lB,
                    pbuf_raw[wv][0][0], pbuf_raw[wv][0][1], l16, quad);
        loadFrags(fa, khb, vhb, jbase + (jt + 2) * 32, l16, quad);  // tail over-read stays in ws
        tileCompute(fb, qA, qB, ones, o00, o10, o01, o11, lA, lB,
                    pbuf_raw[wv][1][0], pbuf_raw[wv][1][1], l16, quad);
    }

    // epilogue: fp32 stores, full 128B line coverage per wave (A+B adjacent)
    float* aos = ao + (size_t)ks * 2097152;
    float* lbs = lbuf + (size_t)ks * 65536;
    float* aoA = aos + (size_t)bh * 32 * NPIX + q0 + l16;
    float* aoB = aoA + 16;
#pragma unroll
    for (int r = 0; r < 4; ++r) {
        aoA[(size_t)(quad * 4 + r) * NPIX]      = o00[r];
        aoA[(size_t)(16 + quad * 4 + r) * NPIX] = o10[r];
        aoB[(size_t)(quad * 4 + r) * NPIX]      = o01[r];
        aoB[(size_t)(16 + quad * 4 + r) * NPIX] = o11[r];
    }
    if (quad == 0) {
        lbs[(size_t)bh * NPIX + q0 + l16]      = lA.x;
        lbs[(size_t)bh * NPIX + q0 + 16 + l16] = lB.x;
    }
}

// ---------------------------------------------------------------------------
// Kernel 3: sum 2 fp32 O-slices (float4), normalize, MFMA projection + bias.
// grid (512, 2): block = 32 px, part = 64-output half. bf16 weights.
// (R7-proven config.)
// ---------------------------------------------------------------------------
__global__ __launch_bounds__(256) void proj_kernel(
    const float* __restrict__ ao, const float* __restrict__ lbuf,
    const unsigned short* __restrict__ wob, const float* __restrict__ b_out,
    float* __restrict__ out)
{
    const int blk  = blockIdx.x;
    const int part = blockIdx.y;
    const int b  = blk >> 7;
    const int n0 = (blk & 127) << 5;
    const int t  = threadIdx.x;
    const int wv = t >> 6;
    const int l16 = t & 15;
    const int quad = (t & 63) >> 4;

    __shared__ unsigned short xsb[32 * 138];   // [pix][c], stride 138
    __shared__ float linv[4][32];

    if (t < 128) {
        int h = t >> 5, p = t & 31;
        size_t li = (size_t)(b * 4 + h) * NPIX + n0 + p;
        linv[h][p] = 1.0f / (lbuf[li] + lbuf[li + 65536]);
    }
    __syncthreads();

    const float* a0 = ao + (size_t)(b * CCH) * NPIX + n0;
    const float* a1 = a0 + 2097152;
#pragma unroll
    for (int k = 0; k < 4; ++k) {
        int idx = k * 256 + t;                 // 1024 float4 slots
        int c = idx >> 3, p4 = (idx & 7) * 4;
        const float4 va = *(const float4*)&a0[(size_t)c * NPIX + p4];
        const float4 vb = *(const float4*)&a1[(size_t)c * NPIX + p4];
        const int hh = c >> 5;
        xsb[(p4 + 0) * 138 + c] = f2bf((va.x + vb.x) * linv[hh][p4 + 0]);
        xsb[(p4 + 1) * 138 + c] = f2bf((va.y + vb.y) * linv[hh][p4 + 1]);
        xsb[(p4 + 2) * 138 + c] = f2bf((va.z + vb.z) * linv[hh][p4 + 2]);
        xsb[(p4 + 3) * 138 + c] = f2bf((va.w + vb.w) * linv[hh][p4 + 3]);
    }
    __syncthreads();

    // A-frags: wob rows (o = o0 + l16), bf16 direct
    const int o0 = part * 64 + wv * 16;
    const unsigned short* wrow = wob + (size_t)(o0 + l16) * CCH;
    bf8 aw[4];
#pragma unroll
    for (int kk = 0; kk < 4; ++kk)
        aw[kk] = *(const bf8*)&wrow[kk * 32 + quad * 8];

    const f4 z = {0.f, 0.f, 0.f, 0.f};
    f4 acc[2] = {z, z};
#pragma unroll
    for (int s = 0; s < 2; ++s) {
#pragma unroll
        for (int kk = 0; kk < 4; ++kk) {
            const unsigned short* row = &xsb[(s * 16 + l16) * 138 + kk * 32 + quad * 8];
            union { unsigned u[4]; bf8 v; } pb;
            pb.u[0] = *(const unsigned*)&row[0];
            pb.u[1] = *(const unsigned*)&row[2];
            pb.u[2] = *(const unsigned*)&row[4];
            pb.u[3] = *(const unsigned*)&row[6];
            acc[s] = MFMA(aw[kk], pb.v, acc[s]);
        }
    }

#pragma unroll
    for (int r = 0; r < 4; ++r) {
        const int o = o0 + quad * 4 + r;
        const float bo = b_out[o];
        float* orow = out + (size_t)(b * CCH + o) * NPIX + n0 + l16;
#pragma unroll
        for (int s = 0; s < 2; ++s)
            orow[s * 16] = acc[s][r] + bo;
    }
}

// ---------------------------------------------------------------------------
extern "C" void kernel_launch(void* const* d_in, const int* in_sizes, int n_in,
                              void* d_out, int out_size, void* d_ws, size_t ws_size,
                              hipStream_t stream) {
    const float* x     = (const float*)d_in[0];
    const float* g     = (const float*)d_in[1];
    const float* bvec  = (const float*)d_in[2];
    const float* w_qkv = (const float*)d_in[3];
    const float* w_out = (const float*)d_in[4];
    const float* b_out = (const float*)d_in[5];
    float* out = (float*)d_out;

    char* ws = (char*)d_ws;
    float*          lbuf = (float*)(ws);                      // 0..512K
    unsigned short* wqb  = (unsigned short*)(ws + (1u << 20));
    unsigned short* wob  = (unsigned short*)(ws + (3u << 19)); // 1.5M
    unsigned short* qh   = (unsigned short*)(ws + (4u  << 20));
    unsigned short* kh   = (unsigned short*)(ws + (8u  << 20));
    unsigned short* vth  = (unsigned short*)(ws + (12u << 20));
    float*          ao   = (float*)(ws + (16u << 20));        // 2 slices x 8MB

    wconv_kernel<<<dim3(256),     dim3(256), 0, stream>>>(w_qkv, w_out, wqb, wob);
    lnqkv_kernel<<<dim3(1024, 2), dim3(256), 0, stream>>>(x, g, bvec, wqb, qh, kh, vth);
    flash_kernel<<<dim3(1024),    dim3(256), 0, stream>>>(qh, kh, vth, ao, lbuf);
    proj_kernel <<<dim3(512, 2),  dim3(256), 0, stream>>>(ao, lbuf, wob, b_out, out);
}

// Round 11
// 185.209 us; speedup vs baseline: 1.8119x; 1.0098x over previous
//
#include <hip/hip_runtime.h>
#include <math.h>

#define NPIX 4096
#define CCH  128

typedef __attribute__((ext_vector_type(8))) short  bf8;   // 8 bf16 in 4 VGPRs
typedef __attribute__((ext_vector_type(4))) float  f4;

#define MFMA(a, b, c) __builtin_amdgcn_mfma_f32_16x16x32_bf16(a, b, c, 0, 0, 0)

__device__ __forceinline__ unsigned short f2bf(float x) {
    union { float f; unsigned u; } v; v.f = x;
    unsigned r = v.u + 0x7fffu + ((v.u >> 16) & 1u);   // RNE
    return (unsigned short)(r >> 16);
}
// pack two floats to bf16x2 (lo in low short), half-ulp RNE, 3 VALU ops
__device__ __forceinline__ unsigned pk2r(float lo, float hi) {
    union { float f; unsigned u; } a, b; a.f = hi; b.f = lo;
    return __builtin_amdgcn_perm(a.u + 0x8000u, b.u + 0x8000u, 0x07060302u);
}
// truncating pack, 1 VALU op. Used ONLY for P in flash: O and l consume the
// same packed P, so the common truncation bias cancels in O/l.
__device__ __forceinline__ unsigned pk2t(float lo, float hi) {
    union { float f; unsigned u; } a, b; a.f = hi; b.f = lo;
    return __builtin_amdgcn_perm(a.u, b.u, 0x07060302u);
}
__device__ __forceinline__ unsigned bperm(int addr, unsigned v) {
    return (unsigned)__builtin_amdgcn_ds_bpermute(addr, (int)v);
}

// Workspace layout (bytes), 32 MB:
//   lbuf 0..512K     fp32 2 slices [bh][n]   (flash out)
//   wqb  1M..1.094M  bf16 [384][128]  (q rows pre-scaled by 32^-.5*log2e)
//   wob  1.5M..1.53M bf16 [128][128]
//   qh   4..8M       bf16 [bh][n][32]
//   kh   8..12M      bf16 [bh][n][32]
//   vth  12..16M     bf16 [bh*32+d][n]
//   ao   16..32M     fp32 2 slices [bh*32+d][n]

// ---------------------------------------------------------------------------
// Kernel 0: convert weights to bf16 (q rows scaled). grid 256 x 256.
// ---------------------------------------------------------------------------
__global__ __launch_bounds__(256) void wconv_kernel(
    const float* __restrict__ wq, const float* __restrict__ wo,
    unsigned short* __restrict__ wqb, unsigned short* __restrict__ wob)
{
    const float qs2 = 0.17677669529663687f * 1.4426950408889634f;
    int i = blockIdx.x * 256 + threadIdx.x;       // 0..65535
    if (i < 49152) {
        float f = wq[i];
        if (i < 16384) f *= qs2;                  // q rows 0..127
        wqb[i] = f2bf(f);
    } else {
        int j = i - 49152;
        wob[j] = f2bf(wo[j]);
    }
}

// ---------------------------------------------------------------------------
// Kernel 1: fused LayerNorm + QKV MFMA GEMM. grid (1024, 2) x 256 thr.
// (R7-proven config.)
// ---------------------------------------------------------------------------
__global__ __launch_bounds__(256, 8) void lnqkv_kernel(
    const float* __restrict__ x, const float* __restrict__ g,
    const float* __restrict__ bvec, const unsigned short* __restrict__ wqb,
    unsigned short* __restrict__ qh, unsigned short* __restrict__ kh,
    unsigned short* __restrict__ vth)
{
    const int blk  = blockIdx.x;
    const int part = blockIdx.y;        // 0: o-tiles 0..11, 1: 12..23
    const int b  = blk >> 8;
    const int n0 = (blk & 255) << 4;
    const int t  = threadIdx.x;

    __shared__ float xs[CCH * 17];             // [c][pix], stride 17
    __shared__ float red0[16][16];
    __shared__ float red1[16][16];
    __shared__ float mean_s[16];
    __shared__ float rstd_s[16];
    __shared__ unsigned short xnb[16 * 138];   // bf16 [pix][c], stride 138

    const float* xb = x + (size_t)b * CCH * NPIX + n0;
#pragma unroll
    for (int k = 0; k < 8; ++k) {
        int e = k * 256 + t;
        int c = e >> 4, p = e & 15;
        xs[c * 17 + p] = xb[(size_t)c * NPIX + p];
    }
    __syncthreads();

    {
        int pix = t & 15, cg = t >> 4;
        float s = 0.f, s2 = 0.f;
#pragma unroll
        for (int cc = 0; cc < 8; ++cc) {
            float v = xs[(cg * 8 + cc) * 17 + pix];
            s += v; s2 += v * v;
        }
        red0[cg][pix] = s; red1[cg][pix] = s2;
    }
    __syncthreads();
    if (t < 16) {
        float s = 0.f, s2 = 0.f;
#pragma unroll
        for (int cg = 0; cg < 16; ++cg) { s += red0[cg][t]; s2 += red1[cg][t]; }
        float mu  = s * (1.f / 128.f);
        float var = s2 * (1.f / 128.f) - mu * mu;
        mean_s[t] = mu;
        rstd_s[t] = rsqrtf(var + 1e-5f);
    }
    __syncthreads();

    // normalize + pack into LDS: thread -> (pix = t>>4, c0 = (t&15)*8)
    {
        const int pix = t >> 4;
        const int c0  = (t & 15) * 8;
        const float mu = mean_s[pix], rs = rstd_s[pix];
#pragma unroll
        for (int i = 0; i < 4; ++i) {
            int c = c0 + 2 * i;
            float f0 = (xs[c * 17 + pix]       - mu) * rs * g[c]     + bvec[c];
            float f1 = (xs[(c + 1) * 17 + pix] - mu) * rs * g[c + 1] + bvec[c + 1];
            *(unsigned*)&xnb[pix * 138 + c] = pk2r(f0, f1);
        }
    }
    __syncthreads();

    // MFMA GEMM: wave wv covers 3 o-tiles of this part.
    const int wv   = t >> 6;
    const int l16  = t & 15;
    const int quad = (t & 63) >> 4;

    for (int it = 0; it < 3; ++it) {
        const int ot = part * 12 + wv * 3 + it;   // 0-7 q, 8-15 k, 16-23 v
        const unsigned short* wr = wqb + (size_t)(ot * 16 + l16) * CCH;
        f4 acc = {0.f, 0.f, 0.f, 0.f};
#pragma unroll
        for (int kk = 0; kk < 4; ++kk) {
            const bf8 a = *(const bf8*)&wr[kk * 32 + quad * 8];
            const unsigned short* xr = &xnb[l16 * 138 + kk * 32 + quad * 8];
            union { unsigned u[4]; bf8 v; } bx;
            bx.u[0] = *(const unsigned*)&xr[0];
            bx.u[1] = *(const unsigned*)&xr[2];
            bx.u[2] = *(const unsigned*)&xr[4];
            bx.u[3] = *(const unsigned*)&xr[6];
            acc = MFMA(a, bx.v, acc);
        }
        // C-frag: col(px)=l16, row o = ot*16 + quad*4 + r
        if (ot < 16) {
            const int h  = (ot >> 1) & 3;
            const int d0 = (ot & 1) * 16 + quad * 4;
            const int bh = b * 4 + h;
            unsigned short* dst = ((ot < 8) ? qh : kh)
                                + ((size_t)bh * NPIX + n0 + l16) * 32 + d0;
            uint2 wp;
            wp.x = pk2r(acc.x, acc.y);
            wp.y = pk2r(acc.z, acc.w);
            *(uint2*)dst = wp;
        } else {
            const int bh = b * 4 + ((ot - 16) >> 1);
            const int dv = ((ot - 16) & 1) * 16 + quad * 4;
#pragma unroll
            for (int r = 0; r < 4; ++r)
                vth[((size_t)bh * 32 + dv + r) * NPIX + n0 + l16] = f2bf(acc[r]);
        }
    }
}

// ---------------------------------------------------------------------------
// Kernel 2: MFMA flash attention — R7 config (split-K 2, fp32 full-line
// stores, grid 1024 = 4 blk/CU, XCD-swizzled) with the P transpose done
// IN-REGISTER via ds_bpermute: zero LDS, no write->read round trip.
// S^T C-frag dwords per src lane (qs,l16): a0x=keys{4qs,4qs+1}, a0y={+2,+3},
// a1x={16+4qs,+1}, a1y={16+4qs+2,+3}, all for q=l16. PV B-frag dword jd of
// dest lane (Q,l16) = word (jd odd ? y : x) of set (Q<2 ? a0 : a1) from
// src lane ((Q&1)*2 + (jd>>1))*16 + l16.
// ---------------------------------------------------------------------------
struct Frags { bf8 k0, k1, v0, v1; };

__device__ __forceinline__ void loadFrags(Frags& f,
    const unsigned short* __restrict__ khb, const unsigned short* __restrict__ vhb,
    int j0, int l16, int quad)
{
    const size_t ka0 = (size_t)(j0 + l16) * 32 + quad * 8;
    f.k0 = *(const bf8*)&khb[ka0];
    f.k1 = *(const bf8*)&khb[ka0 + 16 * 32];
    const size_t va0 = (size_t)l16 * NPIX + j0 + quad * 8;
    f.v0 = *(const bf8*)&vhb[va0];
    f.v1 = *(const bf8*)&vhb[va0 + (size_t)16 * NPIX];
}

__device__ __forceinline__ void tileCompute(const Frags& f,
    const bf8 qA, const bf8 qB, const bf8 ones,
    f4& o00, f4& o10, f4& o01, f4& o11, f4& lA, f4& lB,
    int bp0, int bp1, bool hi)
{
    const f4 z = {0.f, 0.f, 0.f, 0.f};
    f4 sA0 = MFMA(f.k0, qA, z);
    f4 sA1 = MFMA(f.k1, qA, z);
    f4 sB0 = MFMA(f.k0, qB, z);
    f4 sB1 = MFMA(f.k1, qB, z);

    // P = exp2(S), packed as key-pair dwords (truncating)
    const unsigned a0x = pk2t(__builtin_amdgcn_exp2f(sA0.x), __builtin_amdgcn_exp2f(sA0.y));
    const unsigned a0y = pk2t(__builtin_amdgcn_exp2f(sA0.z), __builtin_amdgcn_exp2f(sA0.w));
    const unsigned a1x = pk2t(__builtin_amdgcn_exp2f(sA1.x), __builtin_amdgcn_exp2f(sA1.y));
    const unsigned a1y = pk2t(__builtin_amdgcn_exp2f(sA1.z), __builtin_amdgcn_exp2f(sA1.w));
    const unsigned b0x = pk2t(__builtin_amdgcn_exp2f(sB0.x), __builtin_amdgcn_exp2f(sB0.y));
    const unsigned b0y = pk2t(__builtin_amdgcn_exp2f(sB0.z), __builtin_amdgcn_exp2f(sB0.w));
    const unsigned b1x = pk2t(__builtin_amdgcn_exp2f(sB1.x), __builtin_amdgcn_exp2f(sB1.y));
    const unsigned b1y = pk2t(__builtin_amdgcn_exp2f(sB1.z), __builtin_amdgcn_exp2f(sB1.w));

    // in-register transpose: 16 bpermutes + 8 selects, no LDS buffer
    union { unsigned u[4]; bf8 v; } pA, pB;
    {
        const unsigned d0a = bperm(bp0, a0x), d0b = bperm(bp0, a1x);
        const unsigned d1a = bperm(bp0, a0y), d1b = bperm(bp0, a1y);
        const unsigned d2a = bperm(bp1, a0x), d2b = bperm(bp1, a1x);
        const unsigned d3a = bperm(bp1, a0y), d3b = bperm(bp1, a1y);
        pA.u[0] = hi ? d0b : d0a;
        pA.u[1] = hi ? d1b : d1a;
        pA.u[2] = hi ? d2b : d2a;
        pA.u[3] = hi ? d3b : d3a;
    }
    {
        const unsigned d0a = bperm(bp0, b0x), d0b = bperm(bp0, b1x);
        const unsigned d1a = bperm(bp0, b0y), d1b = bperm(bp0, b1y);
        const unsigned d2a = bperm(bp1, b0x), d2b = bperm(bp1, b1x);
        const unsigned d3a = bperm(bp1, b0y), d3b = bperm(bp1, b1y);
        pB.u[0] = hi ? d0b : d0a;
        pB.u[1] = hi ? d1b : d1a;
        pB.u[2] = hi ? d2b : d2a;
        pB.u[3] = hi ? d3b : d3a;
    }

    o00 = MFMA(f.v0, pA.v, o00); o10 = MFMA(f.v1, pA.v, o10);
    o01 = MFMA(f.v0, pB.v, o01); o11 = MFMA(f.v1, pB.v, o11);
    lA  = MFMA(ones, pA.v, lA);  lB  = MFMA(ones, pB.v, lB);
}

__global__ __launch_bounds__(256, 4) void flash_kernel(
    const unsigned short* __restrict__ qh, const unsigned short* __restrict__ kh,
    const unsigned short* __restrict__ vth,
    float* __restrict__ ao, float* __restrict__ lbuf)
{
    const int blk = blockIdx.x;
    const int bh  = (blk & 7) + 8 * ((blk >> 3) & 1);   // XCD-local per bh
    const int rem = blk >> 4;
    const int qt  = rem & 31;
    const int ks  = rem >> 5;                            // 0..1
    const int t   = threadIdx.x;
    const int wv  = t >> 6;
    const int l16 = t & 15;
    const int quad = (t & 63) >> 4;
    const int q0  = qt * 128 + wv * 32;

    // bpermute source lanes (byte addr): src quads 2*(quad&1) and +1, same l16
    const int bp0 = (((quad & 1) * 32) + l16) << 2;
    const int bp1 = bp0 + (16 << 2);
    const bool hi = quad >= 2;

    const size_t qbaseA = ((size_t)bh * NPIX + q0 + l16) * 32 + quad * 8;
    const bf8 qA = *(const bf8*)&qh[qbaseA];
    const bf8 qB = *(const bf8*)&qh[qbaseA + 16 * 32];

    const unsigned short* khb = kh  + (size_t)bh * NPIX * 32;
    const unsigned short* vhb = vth + (size_t)bh * 32 * NPIX;

    const short one = (short)0x3f80;
    const bf8 ones = {one, one, one, one, one, one, one, one};

    const f4 z = {0.f, 0.f, 0.f, 0.f};
    f4 o00 = z, o10 = z, o01 = z, o11 = z, lA = z, lB = z;

    const int jbase = ks * 2048;
    Frags fa, fb;
    loadFrags(fa, khb, vhb, jbase, l16, quad);
    for (int jt = 0; jt < 64; jt += 2) {
        loadFrags(fb, khb, vhb, jbase + (jt + 1) * 32, l16, quad);
        tileCompute(fa, qA, qB, ones, o00, o10, o01, o11, lA, lB, bp0, bp1, hi);
        loadFrags(fa, khb, vhb, jbase + (jt + 2) * 32, l16, quad);  // tail over-read stays in ws
        tileCompute(fb, qA, qB, ones, o00, o10, o01, o11, lA, lB, bp0, bp1, hi);
    }

    // epilogue: fp32 stores, full 128B line coverage per wave (A+B adjacent)
    float* aos = ao + (size_t)ks * 2097152;
    float* lbs = lbuf + (size_t)ks * 65536;
    float* aoA = aos + (size_t)bh * 32 * NPIX + q0 + l16;
    float* aoB = aoA + 16;
#pragma unroll
    for (int r = 0; r < 4; ++r) {
        aoA[(size_t)(quad * 4 + r) * NPIX]      = o00[r];
        aoA[(size_t)(16 + quad * 4 + r) * NPIX] = o10[r];
        aoB[(size_t)(quad * 4 + r) * NPIX]      = o01[r];
        aoB[(size_t)(16 + quad * 4 + r) * NPIX] = o11[r];
    }
    if (quad == 0) {
        lbs[(size_t)bh * NPIX + q0 + l16]      = lA.x;
        lbs[(size_t)bh * NPIX + q0 + 16 + l16] = lB.x;
    }
}

// ---------------------------------------------------------------------------
// Kernel 3: sum 2 fp32 O-slices (float4), normalize, MFMA projection + bias.
// grid (512, 2). (R7-proven config.)
// ---------------------------------------------------------------------------
__global__ __launch_bounds__(256) void proj_kernel(
    const float* __restrict__ ao, const float* __restrict__ lbuf,
    const unsigned short* __restrict__ wob, const float* __restrict__ b_out,
    float* __restrict__ out)
{
    const int blk  = blockIdx.x;
    const int part = blockIdx.y;
    const int b  = blk >> 7;
    const int n0 = (blk & 127) << 5;
    const int t  = threadIdx.x;
    const int wv = t >> 6;
    const int l16 = t & 15;
    const int quad = (t & 63) >> 4;

    __shared__ unsigned short xsb[32 * 138];   // [pix][c], stride 138
    __shared__ float linv[4][32];

    if (t < 128) {
        int h = t >> 5, p = t & 31;
        size_t li = (size_t)(b * 4 + h) * NPIX + n0 + p;
        linv[h][p] = 1.0f / (lbuf[li] + lbuf[li + 65536]);
    }
    __syncthreads();

    const float* a0 = ao + (size_t)(b * CCH) * NPIX + n0;
    const float* a1 = a0 + 2097152;
#pragma unroll
    for (int k = 0; k < 4; ++k) {
        int idx = k * 256 + t;                 // 1024 float4 slots
        int c = idx >> 3, p4 = (idx & 7) * 4;
        const float4 va = *(const float4*)&a0[(size_t)c * NPIX + p4];
        const float4 vb = *(const float4*)&a1[(size_t)c * NPIX + p4];
        const int hh = c >> 5;
        xsb[(p4 + 0) * 138 + c] = f2bf((va.x + vb.x) * linv[hh][p4 + 0]);
        xsb[(p4 + 1) * 138 + c] = f2bf((va.y + vb.y) * linv[hh][p4 + 1]);
        xsb[(p4 + 2) * 138 + c] = f2bf((va.z + vb.z) * linv[hh][p4 + 2]);
        xsb[(p4 + 3) * 138 + c] = f2bf((va.w + vb.w) * linv[hh][p4 + 3]);
    }
    __syncthreads();

    // A-frags: wob rows (o = o0 + l16), bf16 direct
    const int o0 = part * 64 + wv * 16;
    const unsigned short* wrow = wob + (size_t)(o0 + l16) * CCH;
    bf8 aw[4];
#pragma unroll
    for (int kk = 0; kk < 4; ++kk)
        aw[kk] = *(const bf8*)&wrow[kk * 32 + quad * 8];

    const f4 z = {0.f, 0.f, 0.f, 0.f};
    f4 acc[2] = {z, z};
#pragma unroll
    for (int s = 0; s < 2; ++s) {
#pragma unroll
        for (int kk = 0; kk < 4; ++kk) {
            const unsigned short* row = &xsb[(s * 16 + l16) * 138 + kk * 32 + quad * 8];
            union { unsigned u[4]; bf8 v; } pb;
            pb.u[0] = *(const unsigned*)&row[0];
            pb.u[1] = *(const unsigned*)&row[2];
            pb.u[2] = *(const unsigned*)&row[4];
            pb.u[3] = *(const unsigned*)&row[6];
            acc[s] = MFMA(aw[kk], pb.v, acc[s]);
        }
    }

#pragma unroll
    for (int r = 0; r < 4; ++r) {
        const int o = o0 + quad * 4 + r;
        const float bo = b_out[o];
        float* orow = out + (size_t)(b * CCH + o) * NPIX + n0 + l16;
#pragma unroll
        for (int s = 0; s < 2; ++s)
            orow[s * 16] = acc[s][r] + bo;
    }
}

// ---------------------------------------------------------------------------
extern "C" void kernel_launch(void* const* d_in, const int* in_sizes, int n_in,
                              void* d_out, int out_size, void* d_ws, size_t ws_size,
                              hipStream_t stream) {
    const float* x     = (const float*)d_in[0];
    const float* g     = (const float*)d_in[1];
    const float* bvec  = (const float*)d_in[2];
    const float* w_qkv = (const float*)d_in[3];
    const float* w_out = (const float*)d_in[4];
    const float* b_out = (const float*)d_in[5];
    float* out = (float*)d_out;

    char* ws = (char*)d_ws;
    float*          lbuf = (float*)(ws);                      // 0..512K
    unsigned short* wqb  = (unsigned short*)(ws + (1u << 20));
    unsigned short* wob  = (unsigned short*)(ws + (3u << 19)); // 1.5M
    unsigned short* qh   = (unsigned short*)(ws + (4u  << 20));
    unsigned short* kh   = (unsigned short*)(ws + (8u  << 20));
    unsigned short* vth  = (unsigned short*)(ws + (12u << 20));
    float*          ao   = (float*)(ws + (16u << 20));        // 2 slices x 8MB

    wconv_kernel<<<dim3(256),     dim3(256), 0, stream>>>(w_qkv, w_out, wqb, wob);
    lnqkv_kernel<<<dim3(1024, 2), dim3(256), 0, stream>>>(x, g, bvec, wqb, qh, kh, vth);
    flash_kernel<<<dim3(1024),    dim3(256), 0, stream>>>(qh, kh, vth, ao, lbuf);
    proj_kernel <<<dim3(512, 2),  dim3(256), 0, stream>>>(ao, lbuf, wob, b_out, out);
}